// Round 2
// baseline (294.292 us; speedup 1.0000x reference)
//
#include <hip/hip_runtime.h>
#include <math.h>

#define B_  2
#define N_  2048
#define NT_ 8
#define DZ_ 16
#define H_  64
#define W_  64

#define XGRID_SIZE (B_*NT_*H_*W_*3)   // 196608 floats

// ---------------------------------------------------------------------------
// Fully fused, workspace-free kernel.
//
// Block = one (b, t, i) row of 64 j-pixels. 256 threads = 4 waves.
//   phase 1 (cooperative): uc[n] = { exp2(-(dt^2 + di^2)) [pre-scaled],
//                                    x[n].z * r2 }  for n = 0..2047  (LDS, 16 KB)
//            + write the 192-float x_grid row (first 192 threads, coalesced).
//   phase 2: wave w accumulates n in [w*512, w*512+512); lane = j.
//            per n: ds_read_b64 broadcast of uc[n], 1 sub, 1 mul, 1 exp2,
//            1 mul, then 16 FMA with z[n][e] (wave-uniform address ->
//            expected s_load_dwordx16 on the scalar pipe).
//   phase 3: LDS tree-reduce 4 partial waves -> float4 stores.
//
// exp(-0.5 * sum_d (dx_d/ls_d)^2) == exp2(-sum_d (dx_d * r_d)^2)
//   with r_d = sqrt(0.5 * log2(e)) / ls_d.
// ---------------------------------------------------------------------------
__global__ __launch_bounds__(256) void fused_kernel(
    const float* __restrict__ x,      // [B][N][3]
    const float* __restrict__ z,      // [B][N][16]
    const float* __restrict__ tg,     // [B][NT]
    const float* __restrict__ lsp,    // [3]
    float* __restrict__ out)          // x_grid (196608) ++ z_grid (1048576)
{
    const int i   = blockIdx.x & 63;
    const int t   = (blockIdx.x >> 6) & 7;
    const int b   = blockIdx.x >> 9;
    const int tid = threadIdx.x;
    const int w   = tid >> 6;     // wave id 0..3 = n-chunk
    const int j   = tid & 63;     // lane = spatial j

    const float step = 2.0f / 63.0f;
    const float C    = 0.84932180f;   // sqrt(0.5 * log2(e))

    // ls = 1e-5 + softplus(param); tiny, recompute per thread
    const float r0 = C / (1e-5f + log1pf(expf(lsp[0])));
    const float r1 = C / (1e-5f + log1pf(expf(lsp[1])));
    const float r2 = C / (1e-5f + log1pf(expf(lsp[2])));

    const float tval = tg[b*NT_ + t];
    const float gi   = -1.0f + step * (float)i;

    __shared__ float2 uc[N_];          // 16 KB

    // ---- phase 1: separable (t, y) factor table ----
    const float* __restrict__ xb = x + b*N_*3;
    for (int k = tid; k < N_; k += 256) {
        float x0 = xb[k*3 + 0];
        float x1 = xb[k*3 + 1];
        float x2 = xb[k*3 + 2];
        float dt = (tval - x0) * r0;
        float di = (gi   - x1) * r1;
        float u  = exp2f(-(dt*dt + di*di));
        uc[k] = make_float2(u, x2 * r2);
    }

    // x_grid row for this (b,t,i): 64 pixels * 3 floats, coalesced
    if (tid < 192) {
        int jj = tid / 3;
        int c  = tid - jj*3;
        float gj = -1.0f + step * (float)jj;
        float v  = (c == 0) ? tval : ((c == 1) ? gi : gj);
        out[(size_t)(((b*NT_ + t)*H_ + i)*W_)*3 + tid] = v;
    }

    __syncthreads();

    // ---- phase 2: accumulate over this wave's n-chunk ----
    const float aj = (-1.0f + step * (float)j) * r2;
    const float* __restrict__ zb = z + b*N_*DZ_;

    float acc[DZ_];
    #pragma unroll
    for (int e = 0; e < DZ_; ++e) acc[e] = 0.0f;

    const int n0 = w * (N_/4);
    #pragma unroll 4
    for (int n = n0; n < n0 + N_/4; ++n) {
        float2 p  = uc[n];                 // LDS broadcast
        float d   = aj - p.y;
        float wgt = p.x * exp2f(-(d*d));
        const float* zr = zb + n*DZ_;      // wave-uniform -> scalar loads
        #pragma unroll
        for (int e = 0; e < DZ_; ++e)
            acc[e] = fmaf(wgt, zr[e], acc[e]);
    }

    // ---- phase 3: block reduce 4 partial waves -> 1, then store ----
    __shared__ float red[4][64][DZ_];      // 16 KB
    #pragma unroll
    for (int e = 0; e < DZ_; ++e) red[w][j][e] = acc[e];
    __syncthreads();

    const int jj = tid >> 2;               // 0..63
    const int eg = (tid & 3) * 4;          // 0,4,8,12
    float4 s = make_float4(0.f, 0.f, 0.f, 0.f);
    #pragma unroll
    for (int ww = 0; ww < 4; ++ww) {
        s.x += red[ww][jj][eg + 0];
        s.y += red[ww][jj][eg + 1];
        s.z += red[ww][jj][eg + 2];
        s.w += red[ww][jj][eg + 3];
    }
    float* o = out + XGRID_SIZE
             + ((size_t)(((b*NT_ + t)*H_ + i)*W_ + jj))*DZ_ + eg;
    *(float4*)o = s;
}

extern "C" void kernel_launch(void* const* d_in, const int* in_sizes, int n_in,
                              void* d_out, int out_size, void* d_ws, size_t ws_size,
                              hipStream_t stream) {
    const float* x   = (const float*)d_in[0];   // [B][N][3]
    const float* z   = (const float*)d_in[1];   // [B][N][16]
    const float* tg  = (const float*)d_in[2];   // [B][NT]
    const float* lsp = (const float*)d_in[3];   // [3]

    float* out = (float*)d_out;

    // 2*8*64 = 1024 blocks, one per (b,t,i) row; no workspace used.
    fused_kernel<<<1024, 256, 0, stream>>>(x, z, tg, lsp, out);
}

// Round 3
// 132.698 us; speedup vs baseline: 2.2178x; 2.2178x over previous
//
#include <hip/hip_runtime.h>
#include <math.h>

#define B_  2
#define N_  2048
#define NT_ 8
#define DZ_ 16
#define H_  64
#define W_  64

#define XGRID_SIZE (B_*NT_*H_*W_*3)   // 196608 floats
#define CUT 30.0f                     // exp2(-30) ~ 9.3e-10: drop weight

// ---------------------------------------------------------------------------
// Fused kernel, R3: block-uniform n-compaction + software-pipelined inner loop.
//
// Block = one (b,t,i) row of 64 j-pixels, 256 threads = 4 waves.
// phase 1: cooperative over n: s = (dt*r0)^2 + (di*r1)^2 (block-uniform per n).
//          Keep n iff s < CUT (exp2(-s) > ~1e-9). Wave-ballot stream
//          compaction into LDS: cuc[m] = {exp2(-s), x2*r2}, cidx[m] = n.
//          Also writes the 192-float x_grid row. ~25-30% of n survives.
// phase 2: wave w handles compacted entries {w + 4m}; processes PAIRS
//          (k, k+4) per iteration with next-pair metadata prefetched in
//          registers, so the 8 global z float4 loads issue with no LDS
//          dependency in the loop-carried path. List is zero-padded
//          (16 entries, u=0) so the inner loop has no guards.
// phase 3: LDS tree-reduce 4 partial waves (buffer union'd over the
//          compaction arrays, barrier-separated) -> float4 stores.
// ---------------------------------------------------------------------------
__global__ __launch_bounds__(256) void fused_kernel(
    const float* __restrict__ x,      // [B][N][3]
    const float* __restrict__ z,      // [B][N][16]
    const float* __restrict__ tg,     // [B][NT]
    const float* __restrict__ lsp,    // [3]
    float* __restrict__ out)          // x_grid (196608) ++ z_grid (1048576)
{
    const int i    = blockIdx.x & 63;
    const int t    = (blockIdx.x >> 6) & 7;
    const int b    = blockIdx.x >> 9;
    const int tid  = threadIdx.x;
    const int w    = tid >> 6;     // wave id 0..3
    const int lane = tid & 63;
    const int j    = lane;         // lane = spatial j

    const float step = 2.0f / 63.0f;
    const float C    = 0.84932180f;   // sqrt(0.5 * log2(e))

    const float r0 = C / (1e-5f + log1pf(expf(lsp[0])));
    const float r1 = C / (1e-5f + log1pf(expf(lsp[1])));
    const float r2 = C / (1e-5f + log1pf(expf(lsp[2])));

    const float tval = tg[b*NT_ + t];
    const float gi   = -1.0f + step * (float)i;

    union SM {
        struct { float2 cuc[N_ + 16]; int cidx[N_ + 16]; } c;  // 24768 B
        float red[4][64][DZ_];                                 // 16384 B
    };
    __shared__ SM sm;
    __shared__ int s_cnt;

    if (tid == 0) s_cnt = 0;
    __syncthreads();

    // ---- phase 1: cull + compact the (t,y)-factor table ----
    const float* __restrict__ xb = x + b*N_*3;
    for (int k0 = 0; k0 < N_; k0 += 256) {
        int k = k0 + tid;
        float x0 = xb[k*3 + 0];
        float x1 = xb[k*3 + 1];
        float x2 = xb[k*3 + 2];
        float dt = (tval - x0) * r0;
        float di = (gi   - x1) * r1;
        float s  = dt*dt + di*di;
        bool keep = (s < CUT);
        unsigned long long mb = __ballot(keep);
        int cnt = __popcll(mb);
        int base = 0;
        if (lane == 0) base = atomicAdd(&s_cnt, cnt);
        base = __shfl(base, 0, 64);
        if (keep) {
            int rank = __popcll(mb & ((1ull << lane) - 1ull));
            int pos  = base + rank;
            sm.c.cuc[pos]  = make_float2(exp2f(-s), x2 * r2);
            sm.c.cidx[pos] = k;
        }
    }

    // x_grid row for this (b,t,i): 64 pixels * 3 floats, coalesced
    if (tid < 192) {
        int jj = tid / 3;
        int c  = tid - jj*3;
        float gj = -1.0f + step * (float)jj;
        float v  = (c == 0) ? tval : ((c == 1) ? gi : gj);
        out[(size_t)(((b*NT_ + t)*H_ + i)*W_)*3 + tid] = v;
    }

    __syncthreads();
    const int M = s_cnt;
    if (tid < 16) {                       // zero padding: guard-free inner loop
        sm.c.cuc[M + tid]  = make_float2(0.f, 0.f);
        sm.c.cidx[M + tid] = 0;
    }
    __syncthreads();

    // ---- phase 2: software-pipelined accumulate over compacted list ----
    const float aj = (-1.0f + step * (float)j) * r2;
    const float* __restrict__ zb = z + b*N_*DZ_;

    float acc[DZ_];
    #pragma unroll
    for (int e = 0; e < DZ_; ++e) acc[e] = 0.0f;

    // prologue metadata (safe: indices <= 7 <= M+15 thanks to padding)
    float2 pA = sm.c.cuc[w];
    float2 pB = sm.c.cuc[w + 4];
    int    nA = sm.c.cidx[w];
    int    nB = sm.c.cidx[w + 4];

    for (int k = w; k < M; k += 8) {
        // issue z loads for current pair immediately (no LDS dep)
        const float4* __restrict__ zA = (const float4*)(zb + (size_t)nA * DZ_);
        const float4* __restrict__ zB = (const float4*)(zb + (size_t)nB * DZ_);
        float4 za[4], zbv[4];
        #pragma unroll
        for (int q = 0; q < 4; ++q) za[q]  = zA[q];
        #pragma unroll
        for (int q = 0; q < 4; ++q) zbv[q] = zB[q];

        // prefetch next pair's metadata (padding makes k+8..k+12 safe)
        float2 pA2 = sm.c.cuc[k + 8];
        float2 pB2 = sm.c.cuc[k + 12];
        int    nA2 = sm.c.cidx[k + 8];
        int    nB2 = sm.c.cidx[k + 12];

        float dA = aj - pA.y;
        float dB = aj - pB.y;
        float wA = pA.x * exp2f(-(dA*dA));
        float wB = pB.x * exp2f(-(dB*dB));

        #pragma unroll
        for (int q = 0; q < 4; ++q) {
            acc[4*q + 0] = fmaf(wA, za[q].x, acc[4*q + 0]);
            acc[4*q + 1] = fmaf(wA, za[q].y, acc[4*q + 1]);
            acc[4*q + 2] = fmaf(wA, za[q].z, acc[4*q + 2]);
            acc[4*q + 3] = fmaf(wA, za[q].w, acc[4*q + 3]);
        }
        #pragma unroll
        for (int q = 0; q < 4; ++q) {
            acc[4*q + 0] = fmaf(wB, zbv[q].x, acc[4*q + 0]);
            acc[4*q + 1] = fmaf(wB, zbv[q].y, acc[4*q + 1]);
            acc[4*q + 2] = fmaf(wB, zbv[q].z, acc[4*q + 2]);
            acc[4*q + 3] = fmaf(wB, zbv[q].w, acc[4*q + 3]);
        }

        pA = pA2; pB = pB2; nA = nA2; nB = nB2;
    }

    __syncthreads();   // cuc/cidx reads done before red overlays them

    // ---- phase 3: block reduce 4 partial waves -> 1, then store ----
    #pragma unroll
    for (int e = 0; e < DZ_; ++e) sm.red[w][j][e] = acc[e];
    __syncthreads();

    const int jj = tid >> 2;               // 0..63
    const int eg = (tid & 3) * 4;          // 0,4,8,12
    float4 s4 = make_float4(0.f, 0.f, 0.f, 0.f);
    #pragma unroll
    for (int ww = 0; ww < 4; ++ww) {
        s4.x += sm.red[ww][jj][eg + 0];
        s4.y += sm.red[ww][jj][eg + 1];
        s4.z += sm.red[ww][jj][eg + 2];
        s4.w += sm.red[ww][jj][eg + 3];
    }
    float* o = out + XGRID_SIZE
             + ((size_t)(((b*NT_ + t)*H_ + i)*W_ + jj))*DZ_ + eg;
    *(float4*)o = s4;
}

extern "C" void kernel_launch(void* const* d_in, const int* in_sizes, int n_in,
                              void* d_out, int out_size, void* d_ws, size_t ws_size,
                              hipStream_t stream) {
    const float* x   = (const float*)d_in[0];   // [B][N][3]
    const float* z   = (const float*)d_in[1];   // [B][N][16]
    const float* tg  = (const float*)d_in[2];   // [B][NT]
    const float* lsp = (const float*)d_in[3];   // [3]

    float* out = (float*)d_out;

    // 2*8*64 = 1024 blocks, one per (b,t,i) row; no workspace used.
    fused_kernel<<<1024, 256, 0, stream>>>(x, z, tg, lsp, out);
}

// Round 4
// 108.733 us; speedup vs baseline: 2.7066x; 1.2204x over previous
//
#include <hip/hip_runtime.h>
#include <math.h>

#define B_  2
#define N_  2048
#define NT_ 8
#define DZ_ 16
#define H_  64
#define W_  64

#define NSPLIT 2
#define NCH (N_/NSPLIT)               // 1024 n's per block

#define XGRID_SIZE (B_*NT_*H_*W_*3)   // 196608 floats
#define ZGRID_SIZE (B_*NT_*H_*W_*DZ_) // 1048576 floats
#define CUT 16.0f                     // exp2(-16) ~ 1.5e-5; dropped mass ~5e-4

// ---------------------------------------------------------------------------
// R4: n-split x2 (grid 2048, 8 blocks/CU), CUT 30->16, bank-conflict-free
// reduction buffer (stride 17), atomic combine into pre-zeroed z_grid.
//
// Block = (split s, b, t, i): handles n in [s*1024, s*1024+1024) for one
// (b,t,i) row of 64 j-pixels. 256 threads = 4 waves.
// phase 1: cull s = (dt*r0)^2 + (di*r1)^2 < CUT, ballot-compact into LDS.
// phase 2: wave w processes compacted pairs (k, k+4), k = w + 8m, with
//          next-pair metadata prefetched in registers; 16 fp32 acc/lane.
// phase 3: LDS tree-reduce 4 waves (stride-17 padded = conflict-free),
//          then 4 coalesced global_atomic_add_f32 per thread.
// ---------------------------------------------------------------------------
__global__ __launch_bounds__(256) void fused_kernel(
    const float* __restrict__ x,      // [B][N][3]
    const float* __restrict__ z,      // [B][N][16]
    const float* __restrict__ tg,     // [B][NT]
    const float* __restrict__ lsp,    // [3]
    float* __restrict__ out)          // x_grid (196608) ++ z_grid (1048576)
{
    const int rest = blockIdx.x & 1023;
    const int s    = blockIdx.x >> 10;   // n-split id 0..1
    const int i    = rest & 63;
    const int t    = (rest >> 6) & 7;
    const int b    = rest >> 9;
    const int tid  = threadIdx.x;
    const int w    = tid >> 6;     // wave id 0..3
    const int lane = tid & 63;
    const int j    = lane;         // lane = spatial j

    const float step = 2.0f / 63.0f;
    const float C    = 0.84932180f;   // sqrt(0.5 * log2(e))

    const float r0 = C / (1e-5f + log1pf(expf(lsp[0])));
    const float r1 = C / (1e-5f + log1pf(expf(lsp[1])));
    const float r2 = C / (1e-5f + log1pf(expf(lsp[2])));

    const float tval = tg[b*NT_ + t];
    const float gi   = -1.0f + step * (float)i;

    union SM {
        struct { float2 cuc[NCH + 16]; int cidx[NCH + 16]; } c;  // 12480 B
        float red[4][64][DZ_ + 1];                               // 17408 B
    };
    __shared__ SM sm;
    __shared__ int s_cnt;

    if (tid == 0) s_cnt = 0;
    __syncthreads();

    // ---- phase 1: cull + compact this split's n-chunk ----
    const int nbase = s * NCH;
    const float* __restrict__ xb = x + (b*N_ + nbase)*3;
    for (int k0 = 0; k0 < NCH; k0 += 256) {
        int k = k0 + tid;
        float x0 = xb[k*3 + 0];
        float x1 = xb[k*3 + 1];
        float x2 = xb[k*3 + 2];
        float dt = (tval - x0) * r0;
        float di = (gi   - x1) * r1;
        float sq = dt*dt + di*di;
        bool keep = (sq < CUT);
        unsigned long long mb = __ballot(keep);
        int cnt = __popcll(mb);
        int base = 0;
        if (lane == 0) base = atomicAdd(&s_cnt, cnt);
        base = __shfl(base, 0, 64);
        if (keep) {
            int rank = __popcll(mb & ((1ull << lane) - 1ull));
            int pos  = base + rank;
            sm.c.cuc[pos]  = make_float2(exp2f(-sq), x2 * r2);
            sm.c.cidx[pos] = nbase + k;
        }
    }

    // x_grid row for this (b,t,i): written once (split 0 only), coalesced
    if (s == 0 && tid < 192) {
        int jj = tid / 3;
        int c  = tid - jj*3;
        float gj = -1.0f + step * (float)jj;
        float v  = (c == 0) ? tval : ((c == 1) ? gi : gj);
        out[(size_t)(((b*NT_ + t)*H_ + i)*W_)*3 + tid] = v;
    }

    __syncthreads();
    const int M = s_cnt;
    if (tid < 16) {                       // zero padding: guard-free inner loop
        sm.c.cuc[M + tid]  = make_float2(0.f, 0.f);
        sm.c.cidx[M + tid] = 0;
    }
    __syncthreads();

    // ---- phase 2: software-pipelined accumulate over compacted list ----
    const float aj = (-1.0f + step * (float)j) * r2;
    const float* __restrict__ zb = z + b*N_*DZ_;

    float acc[DZ_];
    #pragma unroll
    for (int e = 0; e < DZ_; ++e) acc[e] = 0.0f;

    float2 pA = sm.c.cuc[w];
    float2 pB = sm.c.cuc[w + 4];
    int    nA = sm.c.cidx[w];
    int    nB = sm.c.cidx[w + 4];

    for (int k = w; k < M; k += 8) {
        const float4* __restrict__ zA = (const float4*)(zb + (size_t)nA * DZ_);
        const float4* __restrict__ zB = (const float4*)(zb + (size_t)nB * DZ_);
        float4 za[4], zbv[4];
        #pragma unroll
        for (int q = 0; q < 4; ++q) za[q]  = zA[q];
        #pragma unroll
        for (int q = 0; q < 4; ++q) zbv[q] = zB[q];

        float2 pA2 = sm.c.cuc[k + 8];
        float2 pB2 = sm.c.cuc[k + 12];
        int    nA2 = sm.c.cidx[k + 8];
        int    nB2 = sm.c.cidx[k + 12];

        float dA = aj - pA.y;
        float dB = aj - pB.y;
        float wA = pA.x * exp2f(-(dA*dA));
        float wB = pB.x * exp2f(-(dB*dB));

        #pragma unroll
        for (int q = 0; q < 4; ++q) {
            acc[4*q + 0] = fmaf(wA, za[q].x, acc[4*q + 0]);
            acc[4*q + 1] = fmaf(wA, za[q].y, acc[4*q + 1]);
            acc[4*q + 2] = fmaf(wA, za[q].z, acc[4*q + 2]);
            acc[4*q + 3] = fmaf(wA, za[q].w, acc[4*q + 3]);
        }
        #pragma unroll
        for (int q = 0; q < 4; ++q) {
            acc[4*q + 0] = fmaf(wB, zbv[q].x, acc[4*q + 0]);
            acc[4*q + 1] = fmaf(wB, zbv[q].y, acc[4*q + 1]);
            acc[4*q + 2] = fmaf(wB, zbv[q].z, acc[4*q + 2]);
            acc[4*q + 3] = fmaf(wB, zbv[q].w, acc[4*q + 3]);
        }

        pA = pA2; pB = pB2; nA = nA2; nB = nB2;
    }

    __syncthreads();   // cuc/cidx reads done before red overlays them

    // ---- phase 3: block reduce (stride-17 = conflict-free), atomic store ----
    #pragma unroll
    for (int e = 0; e < DZ_; ++e) sm.red[w][j][e] = acc[e];
    __syncthreads();

    const int jj = tid >> 2;               // 0..63
    const int eg = (tid & 3) * 4;          // 0,4,8,12
    float4 s4 = make_float4(0.f, 0.f, 0.f, 0.f);
    #pragma unroll
    for (int ww = 0; ww < 4; ++ww) {
        s4.x += sm.red[ww][jj][eg + 0];
        s4.y += sm.red[ww][jj][eg + 1];
        s4.z += sm.red[ww][jj][eg + 2];
        s4.w += sm.red[ww][jj][eg + 3];
    }
    float* o = out + XGRID_SIZE
             + ((size_t)(((b*NT_ + t)*H_ + i)*W_ + jj))*DZ_ + eg;
    atomicAdd(o + 0, s4.x);
    atomicAdd(o + 1, s4.y);
    atomicAdd(o + 2, s4.z);
    atomicAdd(o + 3, s4.w);
}

extern "C" void kernel_launch(void* const* d_in, const int* in_sizes, int n_in,
                              void* d_out, int out_size, void* d_ws, size_t ws_size,
                              hipStream_t stream) {
    const float* x   = (const float*)d_in[0];   // [B][N][3]
    const float* z   = (const float*)d_in[1];   // [B][N][16]
    const float* tg  = (const float*)d_in[2];   // [B][NT]
    const float* lsp = (const float*)d_in[3];   // [3]

    float* out = (float*)d_out;

    // zero z_grid (atomic accumulation target); graph-capturable async memset
    hipMemsetAsync((void*)(out + XGRID_SIZE), 0,
                   (size_t)ZGRID_SIZE * sizeof(float), stream);

    // 2 n-splits * 2*8*64 rows = 2048 blocks (8 per CU); no workspace used.
    fused_kernel<<<2048, 256, 0, stream>>>(x, z, tg, lsp, out);
}